// Round 6
// baseline (224.640 us; speedup 1.0000x reference)
//
#include <hip/hip_runtime.h>

#define N_NODES 50000
#define N_EDGES 800000
#define IN_CH 128
#define HID 64
#define N_CLASSES 10

#define BSH 8                    // 256 nodes per bucket
#define BNODES 256
#define NBKT ((N_NODES + BNODES - 1) / BNODES)   // 196
#define EPB 4096                 // edges per binA block
#define BINCAP 6144              // capacity per bucket (mean 4096, +32 sigma)
#define SLOTS 64                 // padded slots per node (max deg ~40)

// ---------------- phase A: bucket edges by dst range ----------------
// per-(block,bucket) windows reserved atomically; writes within a window are
// consecutive and same-CU -> merge in L2.

__global__ void k_binA(const int* __restrict__ src, const int* __restrict__ dst,
                       int* __restrict__ gCur, unsigned* __restrict__ binned, int ne) {
    __shared__ int hist[NBKT];
    __shared__ int gbase[NBKT];
    __shared__ int lcur[NBKT];
    const int tid = threadIdx.x;
    const int e0 = blockIdx.x * EPB;
    const int ecnt = min(EPB, ne - e0);

    for (int b = tid; b < NBKT; b += 256) { hist[b] = 0; lcur[b] = 0; }
    __syncthreads();
    for (int i = tid; i < ecnt; i += 256)
        atomicAdd(&hist[dst[e0 + i] >> BSH], 1);
    __syncthreads();
    if (tid < NBKT) gbase[tid] = atomicAdd(&gCur[tid], hist[tid]);
    __syncthreads();
    for (int i = tid; i < ecnt; i += 256) {
        int s = src[e0 + i];
        int d = dst[e0 + i];
        int b = d >> BSH;
        int p = atomicAdd(&lcur[b], 1);
        int idx = gbase[b] + p;
        if (idx < BINCAP)
            binned[(size_t)b * BINCAP + idx] = ((unsigned)s << BSH) | (unsigned)(d & (BNODES - 1));
    }
}

// ---------------- phase B: bucket -> padded CSR tile in LDS ----------------

__global__ void k_binB(const int* __restrict__ gCur, const unsigned* __restrict__ binned,
                       unsigned short* __restrict__ col, int* __restrict__ deg,
                       float* __restrict__ dis, int n) {
    __shared__ unsigned short lcol[BNODES * SLOTS];   // 32 KB
    __shared__ int lcur[BNODES];                      // 1 KB
    const int b = blockIdx.x;
    const int tid = threadIdx.x;
    const int nodeBase = b << BSH;
    const int nloc = min(BNODES, n - nodeBase);

    for (int i = tid; i < BNODES; i += 256) lcur[i] = 0;
    __syncthreads();

    const int cnt = min(gCur[b], BINCAP);
    for (int i = tid; i < cnt; i += 256) {
        unsigned v = binned[(size_t)b * BINCAP + i];
        int dl = (int)(v & (BNODES - 1));
        int s = (int)(v >> BSH);
        int p = atomicAdd(&lcur[dl], 1);
        if (p < SLOTS) lcol[dl * SLOTS + p] = (unsigned short)s;
    }
    __syncthreads();

    const uint4* lv = (const uint4*)lcol;
    uint4* gv = (uint4*)(col + (size_t)nodeBase * SLOTS);
    for (int i = tid; i < nloc * 8; i += 256) gv[i] = lv[i];
    for (int i = tid; i < nloc; i += 256) {
        int d2 = min(lcur[i], SLOTS);
        deg[nodeBase + i] = d2;
        dis[nodeBase + i] = rsqrtf((float)(d2 + 1));
    }
}

// ============ shuffle GEMM: out[n,64] = dis[i] * (h[n,K] @ W[K,64]) ============
// No LDS: each wave handles 8 nodes; lane=output col; h rows live in regs,
// broadcast to the wave via __shfl.

__global__ void k_gemm128(const float* __restrict__ h, const float* __restrict__ W,
                          const float* __restrict__ dis, float* __restrict__ out, int n) {
    const int lane = threadIdx.x & 63;
    const int wv = threadIdx.x >> 6;
    const int nd0 = (blockIdx.x * 4 + wv) * 8;

    float2 hr[8];
    #pragma unroll
    for (int i = 0; i < 8; ++i) {
        int nd = min(nd0 + i, n - 1);
        hr[i] = ((const float2*)(h + (size_t)nd * 128))[lane];
    }
    float acc[8];
    #pragma unroll
    for (int i = 0; i < 8; ++i) acc[i] = 0.f;

    #pragma unroll 4
    for (int kk = 0; kk < 64; ++kk) {
        float w0 = W[(2 * kk + 0) * 64 + lane];
        float w1 = W[(2 * kk + 1) * 64 + lane];
        #pragma unroll
        for (int i = 0; i < 8; ++i) {
            acc[i] += __shfl(hr[i].x, kk) * w0;
            acc[i] += __shfl(hr[i].y, kk) * w1;
        }
    }
    #pragma unroll
    for (int i = 0; i < 8; ++i) {
        int nd = nd0 + i;
        if (nd < n) out[(size_t)nd * 64 + lane] = acc[i] * dis[nd];
    }
}

__global__ void k_gemm64s(const float* __restrict__ h, const float* __restrict__ W,
                          const float* __restrict__ dis, float* __restrict__ out, int n) {
    const int lane = threadIdx.x & 63;
    const int wv = threadIdx.x >> 6;
    const int nd0 = (blockIdx.x * 4 + wv) * 8;

    float hr[8];
    #pragma unroll
    for (int i = 0; i < 8; ++i) {
        int nd = min(nd0 + i, n - 1);
        hr[i] = h[(size_t)nd * 64 + lane];
    }
    float acc[8];
    #pragma unroll
    for (int i = 0; i < 8; ++i) acc[i] = 0.f;

    #pragma unroll 4
    for (int k = 0; k < 64; ++k) {
        float wk = W[k * 64 + lane];
        #pragma unroll
        for (int i = 0; i < 8; ++i) acc[i] += __shfl(hr[i], k) * wk;
    }
    #pragma unroll
    for (int i = 0; i < 8; ++i) {
        int nd = nd0 + i;
        if (nd < n) out[(size_t)nd * 64 + lane] = acc[i] * dis[nd];
    }
}

// ============ aggregation: h = relu(dis[d]*(hwp[d] + sum hwp[s]) + b) ============
// one wave per node; LAST=true fuses the 64->10 classifier via a 1KB LDS tile
// (h2 never hits global memory).

template <bool LAST>
__global__ void k_agg(const int* __restrict__ deg, const unsigned short* __restrict__ col,
                      const float* __restrict__ dis, const float* __restrict__ hwp,
                      const float* __restrict__ b, const float* __restrict__ Wc,
                      const float* __restrict__ bc, float* __restrict__ outp, int n) {
    __shared__ float sh2[4][64];
    const int tid = threadIdx.x;
    const int lane = tid & 63;
    const int wv = tid >> 6;
    const int node = blockIdx.x * 4 + wv;

    float h2 = 0.f;
    if (node < n) {
        const int m = deg[node];
        const int rb = node * 64;
        float acc0 = hwp[rb + lane];   // self-loop (dis-scaled in gemm epilogue)
        float acc1 = 0.f, acc2 = 0.f, acc3 = 0.f;
        int s = (lane < m) ? (int)col[(size_t)node * SLOTS + lane] : 0;
        int q = 0;
        for (; q + 8 <= m; q += 8) {
            int s0 = __shfl(s, q + 0), s1 = __shfl(s, q + 1);
            int s2 = __shfl(s, q + 2), s3 = __shfl(s, q + 3);
            int s4 = __shfl(s, q + 4), s5 = __shfl(s, q + 5);
            int s6 = __shfl(s, q + 6), s7 = __shfl(s, q + 7);
            float v0 = hwp[s0 * 64 + lane], v1 = hwp[s1 * 64 + lane];
            float v2 = hwp[s2 * 64 + lane], v3 = hwp[s3 * 64 + lane];
            float v4 = hwp[s4 * 64 + lane], v5 = hwp[s5 * 64 + lane];
            float v6 = hwp[s6 * 64 + lane], v7 = hwp[s7 * 64 + lane];
            acc0 += v0 + v4;
            acc1 += v1 + v5;
            acc2 += v2 + v6;
            acc3 += v3 + v7;
        }
        for (; q + 4 <= m; q += 4) {
            int s0 = __shfl(s, q + 0), s1 = __shfl(s, q + 1);
            int s2 = __shfl(s, q + 2), s3 = __shfl(s, q + 3);
            acc0 += hwp[s0 * 64 + lane];
            acc1 += hwp[s1 * 64 + lane];
            acc2 += hwp[s2 * 64 + lane];
            acc3 += hwp[s3 * 64 + lane];
        }
        for (; q < m; ++q) {
            int s0 = __shfl(s, q);
            acc0 += hwp[s0 * 64 + lane];
        }
        float acc = (acc0 + acc1) + (acc2 + acc3);
        h2 = fmaxf(acc * dis[node] + b[lane], 0.f);
        if (!LAST) outp[(size_t)node * 64 + lane] = h2;
    }

    if (LAST) {
        sh2[wv][lane] = h2;
        __syncthreads();
        if (tid < 4 * N_CLASSES) {
            const int nl = tid / N_CLASSES;
            const int cls = tid - nl * N_CLASSES;
            const int nd = blockIdx.x * 4 + nl;
            if (nd < n) {
                float acc = bc[cls];
                #pragma unroll 8
                for (int k = 0; k < 64; ++k) acc += sh2[nl][k] * Wc[k * N_CLASSES + cls];
                outp[(size_t)nd * N_CLASSES + cls] = acc;
            }
        }
    }
}

extern "C" void kernel_launch(void* const* d_in, const int* in_sizes, int n_in,
                              void* d_out, int out_size, void* d_ws, size_t ws_size,
                              hipStream_t stream) {
    const float* x  = (const float*)d_in[0];
    const int*   ei = (const int*)d_in[1];
    const float* W1 = (const float*)d_in[2];
    const float* b1 = (const float*)d_in[3];
    const float* W2 = (const float*)d_in[4];
    const float* b2 = (const float*)d_in[5];
    const float* Wc = (const float*)d_in[6];
    const float* bc = (const float*)d_in[7];
    float* out = (float*)d_out;

    const int n = N_NODES;
    const int ne = N_EDGES;
    const int* src = ei;
    const int* dst = ei + ne;

    // workspace layout
    float*          bufA   = (float*)d_ws;                              // [n*64]
    float*          bufB   = bufA + (size_t)n * 64;                     // [n*64]
    unsigned short* colu16 = (unsigned short*)(bufB + (size_t)n * 64);  // [NBKT*256*64]
    unsigned*       binned = (unsigned*)(colu16 + (size_t)NBKT * BNODES * SLOTS);
    float*          dis    = (float*)(binned + (size_t)NBKT * BINCAP);  // [n]
    int*            deg    = (int*)(dis + n);                           // [n]
    int*            gCur   = deg + n;                                   // [NBKT]

    const int BS = 256;
    const int gA = (ne + EPB - 1) / EPB;    // 196
    const int gW = (n + 3) / 4;             // 12500
    const int gG = (n + 31) / 32;           // 1563

    // CSR build
    hipMemsetAsync(gCur, 0, NBKT * sizeof(int), stream);
    k_binA<<<gA, BS, 0, stream>>>(src, dst, gCur, binned, ne);
    k_binB<<<NBKT, BS, 0, stream>>>(gCur, binned, colu16, deg, dis, n);

    // layer 1
    k_gemm128<<<gG, BS, 0, stream>>>(x, W1, dis, bufA, n);
    k_agg<false><<<gW, BS, 0, stream>>>(deg, colu16, dis, bufA, b1, nullptr, nullptr, bufB, n);

    // layer 2 + fused classifier
    k_gemm64s<<<gG, BS, 0, stream>>>(bufB, W2, dis, bufA, n);
    k_agg<true><<<gW, BS, 0, stream>>>(deg, colu16, dis, bufA, b2, Wc, bc, out, n);
}

// Round 7
// 152.718 us; speedup vs baseline: 1.4709x; 1.4709x over previous
//
#include <hip/hip_runtime.h>

#define N_NODES 50000
#define N_EDGES 800000
#define IN_CH 128
#define HID 64
#define N_CLASSES 10

#define BSH 8                    // 256 nodes per bucket
#define BNODES 256
#define NBKT ((N_NODES + BNODES - 1) / BNODES)   // 196
#define EPB 4096                 // edges per binA block
#define BINCAP 6144              // capacity per bucket (mean 4096, +32 sigma)
#define SLOTS 64                 // padded slots per node (max deg ~40)

// ---------------- phase A: bucket edges by dst range ----------------
// per-(block,bucket) windows reserved atomically; writes within a window are
// consecutive and same-CU -> merge in L2.

__global__ void k_binA(const int* __restrict__ src, const int* __restrict__ dst,
                       int* __restrict__ gCur, unsigned* __restrict__ binned, int ne) {
    __shared__ int hist[NBKT];
    __shared__ int gbase[NBKT];
    __shared__ int lcur[NBKT];
    const int tid = threadIdx.x;
    const int e0 = blockIdx.x * EPB;
    const int ecnt = min(EPB, ne - e0);

    for (int b = tid; b < NBKT; b += 256) { hist[b] = 0; lcur[b] = 0; }
    __syncthreads();
    for (int i = tid; i < ecnt; i += 256)
        atomicAdd(&hist[dst[e0 + i] >> BSH], 1);
    __syncthreads();
    if (tid < NBKT) gbase[tid] = atomicAdd(&gCur[tid], hist[tid]);
    __syncthreads();
    for (int i = tid; i < ecnt; i += 256) {
        int s = src[e0 + i];
        int d = dst[e0 + i];
        int b = d >> BSH;
        int p = atomicAdd(&lcur[b], 1);
        int idx = gbase[b] + p;
        if (idx < BINCAP)
            binned[(size_t)b * BINCAP + idx] = ((unsigned)s << BSH) | (unsigned)(d & (BNODES - 1));
    }
}

// ---------------- phase B: bucket -> padded CSR tile in LDS ----------------

__global__ void k_binB(const int* __restrict__ gCur, const unsigned* __restrict__ binned,
                       unsigned short* __restrict__ col, int* __restrict__ deg,
                       float* __restrict__ dis, int n) {
    __shared__ unsigned short lcol[BNODES * SLOTS];   // 32 KB
    __shared__ int lcur[BNODES];                      // 1 KB
    const int b = blockIdx.x;
    const int tid = threadIdx.x;
    const int nodeBase = b << BSH;
    const int nloc = min(BNODES, n - nodeBase);

    for (int i = tid; i < BNODES; i += 256) lcur[i] = 0;
    __syncthreads();

    const int cnt = min(gCur[b], BINCAP);
    for (int i = tid; i < cnt; i += 256) {
        unsigned v = binned[(size_t)b * BINCAP + i];
        int dl = (int)(v & (BNODES - 1));
        int s = (int)(v >> BSH);
        int p = atomicAdd(&lcur[dl], 1);
        if (p < SLOTS) lcol[dl * SLOTS + p] = (unsigned short)s;
    }
    __syncthreads();

    const uint4* lv = (const uint4*)lcol;
    uint4* gv = (uint4*)(col + (size_t)nodeBase * SLOTS);
    for (int i = tid; i < nloc * 8; i += 256) gv[i] = lv[i];
    for (int i = tid; i < nloc; i += 256) {
        int d2 = min(lcur[i], SLOTS);
        deg[nodeBase + i] = d2;
        dis[nodeBase + i] = rsqrtf((float)(d2 + 1));
    }
}

// ============ dense GEMM: out[n,64] = dis[i] * (h[n,K] @ W[K,64]) ============
// LDS-staged tile (32 nodes), b128 broadcast reads: per k-quad each thread does
// 8 ds_read_b128 (same-address broadcast) + 4 coalesced W loads + 32 FMA.

template <int K>
__global__ void k_gemm64(const float* __restrict__ h, const float* __restrict__ W,
                         const float* __restrict__ dis, float* __restrict__ out, int n) {
    __shared__ float xs[32][K];
    const int tid = threadIdx.x;
    const int col = tid & 63;
    const int wv = tid >> 6;
    const int nodeBase = blockIdx.x * 32;

    const int total4 = 32 * K / 4;
    const float4* hv = (const float4*)(h + (size_t)nodeBase * K);
    float4* xv = (float4*)&xs[0][0];
    if (nodeBase + 32 <= n) {
        for (int i = tid; i < total4; i += 256) xv[i] = hv[i];
    } else {
        for (int i = tid; i < total4; i += 256) {
            int r = (i * 4) / K;
            float4 z = make_float4(0.f, 0.f, 0.f, 0.f);
            xv[i] = (nodeBase + r < n) ? hv[i] : z;
        }
    }
    __syncthreads();

    float a[8];
    #pragma unroll
    for (int i = 0; i < 8; ++i) a[i] = 0.f;
    const int r0 = wv * 8;
    #pragma unroll 2
    for (int k = 0; k < K; k += 4) {
        float w0 = W[(k + 0) * 64 + col];
        float w1 = W[(k + 1) * 64 + col];
        float w2 = W[(k + 2) * 64 + col];
        float w3 = W[(k + 3) * 64 + col];
        #pragma unroll
        for (int i = 0; i < 8; ++i) {
            float4 xk = *(const float4*)&xs[r0 + i][k];
            a[i] += xk.x * w0 + xk.y * w1 + xk.z * w2 + xk.w * w3;
        }
    }
    #pragma unroll
    for (int i = 0; i < 8; ++i) {
        int nd = nodeBase + r0 + i;
        if (nd < n) out[(size_t)nd * 64 + col] = a[i] * dis[nd];
    }
}

// ============ aggregation: h = relu(dis[d]*(hwp[d] + sum hwp[s]) + b) ============
// one wave per node; LAST=true fuses the 64->10 classifier via a 1KB LDS tile.

template <bool LAST>
__global__ void k_agg(const int* __restrict__ deg, const unsigned short* __restrict__ col,
                      const float* __restrict__ dis, const float* __restrict__ hwp,
                      const float* __restrict__ b, const float* __restrict__ Wc,
                      const float* __restrict__ bc, float* __restrict__ outp, int n) {
    __shared__ float sh2[4][64];
    const int tid = threadIdx.x;
    const int lane = tid & 63;
    const int wv = tid >> 6;
    const int node = blockIdx.x * 4 + wv;

    float h2 = 0.f;
    if (node < n) {
        const int m = deg[node];
        const int rb = node * 64;
        float acc0 = hwp[rb + lane];   // self-loop (dis-scaled in gemm epilogue)
        float acc1 = 0.f, acc2 = 0.f, acc3 = 0.f;
        int s = (lane < m) ? (int)col[(size_t)node * SLOTS + lane] : 0;
        int q = 0;
        for (; q + 8 <= m; q += 8) {
            int s0 = __shfl(s, q + 0), s1 = __shfl(s, q + 1);
            int s2 = __shfl(s, q + 2), s3 = __shfl(s, q + 3);
            int s4 = __shfl(s, q + 4), s5 = __shfl(s, q + 5);
            int s6 = __shfl(s, q + 6), s7 = __shfl(s, q + 7);
            float v0 = hwp[s0 * 64 + lane], v1 = hwp[s1 * 64 + lane];
            float v2 = hwp[s2 * 64 + lane], v3 = hwp[s3 * 64 + lane];
            float v4 = hwp[s4 * 64 + lane], v5 = hwp[s5 * 64 + lane];
            float v6 = hwp[s6 * 64 + lane], v7 = hwp[s7 * 64 + lane];
            acc0 += v0 + v4;
            acc1 += v1 + v5;
            acc2 += v2 + v6;
            acc3 += v3 + v7;
        }
        for (; q + 4 <= m; q += 4) {
            int s0 = __shfl(s, q + 0), s1 = __shfl(s, q + 1);
            int s2 = __shfl(s, q + 2), s3 = __shfl(s, q + 3);
            acc0 += hwp[s0 * 64 + lane];
            acc1 += hwp[s1 * 64 + lane];
            acc2 += hwp[s2 * 64 + lane];
            acc3 += hwp[s3 * 64 + lane];
        }
        for (; q < m; ++q) {
            int s0 = __shfl(s, q);
            acc0 += hwp[s0 * 64 + lane];
        }
        float acc = (acc0 + acc1) + (acc2 + acc3);
        h2 = fmaxf(acc * dis[node] + b[lane], 0.f);
        if (!LAST) outp[(size_t)node * 64 + lane] = h2;
    }

    if (LAST) {
        sh2[wv][lane] = h2;
        __syncthreads();
        if (tid < 4 * N_CLASSES) {
            const int nl = tid / N_CLASSES;
            const int cls = tid - nl * N_CLASSES;
            const int nd = blockIdx.x * 4 + nl;
            if (nd < n) {
                float acc = bc[cls];
                #pragma unroll 8
                for (int k = 0; k < 64; ++k) acc += sh2[nl][k] * Wc[k * N_CLASSES + cls];
                outp[(size_t)nd * N_CLASSES + cls] = acc;
            }
        }
    }
}

extern "C" void kernel_launch(void* const* d_in, const int* in_sizes, int n_in,
                              void* d_out, int out_size, void* d_ws, size_t ws_size,
                              hipStream_t stream) {
    const float* x  = (const float*)d_in[0];
    const int*   ei = (const int*)d_in[1];
    const float* W1 = (const float*)d_in[2];
    const float* b1 = (const float*)d_in[3];
    const float* W2 = (const float*)d_in[4];
    const float* b2 = (const float*)d_in[5];
    const float* Wc = (const float*)d_in[6];
    const float* bc = (const float*)d_in[7];
    float* out = (float*)d_out;

    const int n = N_NODES;
    const int ne = N_EDGES;
    const int* src = ei;
    const int* dst = ei + ne;

    // workspace layout
    float*          bufA   = (float*)d_ws;                              // [n*64]
    float*          bufB   = bufA + (size_t)n * 64;                     // [n*64]
    unsigned short* colu16 = (unsigned short*)(bufB + (size_t)n * 64);  // [NBKT*256*64]
    unsigned*       binned = (unsigned*)(colu16 + (size_t)NBKT * BNODES * SLOTS);
    float*          dis    = (float*)(binned + (size_t)NBKT * BINCAP);  // [n]
    int*            deg    = (int*)(dis + n);                           // [n]
    int*            gCur   = deg + n;                                   // [NBKT]

    const int BS = 256;
    const int gA = (ne + EPB - 1) / EPB;    // 196
    const int gW = (n + 3) / 4;             // 12500
    const int gG = (n + 31) / 32;           // 1563

    // CSR build
    hipMemsetAsync(gCur, 0, NBKT * sizeof(int), stream);
    k_binA<<<gA, BS, 0, stream>>>(src, dst, gCur, binned, ne);
    k_binB<<<NBKT, BS, 0, stream>>>(gCur, binned, colu16, deg, dis, n);

    // layer 1
    k_gemm64<IN_CH><<<gG, BS, 0, stream>>>(x, W1, dis, bufA, n);
    k_agg<false><<<gW, BS, 0, stream>>>(deg, colu16, dis, bufA, b1, nullptr, nullptr, bufB, n);

    // layer 2 + fused classifier
    k_gemm64<HID><<<gG, BS, 0, stream>>>(bufB, W2, dis, bufA, n);
    k_agg<true><<<gW, BS, 0, stream>>>(deg, colu16, dis, bufA, b2, Wc, bc, out, n);
}